// Round 4
// baseline (197.988 us; speedup 1.0000x reference)
//
#include <hip/hip_runtime.h>
#include <hip/hip_bf16.h>

#define N_NODES 50000
#define N_EDGES 200000
// IN_C = 32, HID = 32, OUT_C = 16, EDGE_DIM = 8, EPS = 1e-5

typedef float v2f __attribute__((ext_vector_type(2)));

static __device__ inline v2f sp2(float s) { v2f r; r.x = s; r.y = s; return r; }

static __device__ inline v2f fma2(v2f a, v2f b, v2f c) {
#if __has_builtin(__builtin_elementwise_fma)
    return __builtin_elementwise_fma(a, b, c);
#else
    v2f r; r.x = fmaf(a.x, b.x, c.x); r.y = fmaf(a.y, b.y, c.y); return r;
#endif
}

static __device__ inline v2f max2(v2f a, v2f b) {
#if __has_builtin(__builtin_elementwise_max)
    return __builtin_elementwise_max(a, b);
#else
    v2f r; r.x = fmaxf(a.x, b.x); r.y = fmaxf(a.y, b.y); return r;
#endif
}

// ---------------------------------------------------------------------------
// Edge kernel. Lane = (i4 = lane>>4 in 0..3, oo = lane&15 -> o-pair {2oo,2oo+1}).
// Per edge: W[i][o] = relu(sum_k ea[k]*nn_w[k][i*32+o] + nn_b[i*32+o]);
//           msg[o] = sum_i x[src][i]*W[i][o];  atomicAdd agg[dst][o].
// Weights VGPR-resident via volatile preload (not rematerializable).
// Depth-2 x prefetch + depth-3 scalar metadata, 3-slot rotation, unroll-3.
// ---------------------------------------------------------------------------
__global__ __launch_bounds__(256, 2) void edge_kernel(
    const float* __restrict__ x, const int* __restrict__ ei,
    const float* __restrict__ ea, const float* __restrict__ nn_w,
    const float* __restrict__ nn_b, float* __restrict__ agg)
{
    const int lane = threadIdx.x & 63;
    const int oo   = lane & 15;        // o-pair: o in {2oo, 2oo+1}
    const int i4   = lane >> 4;        // i-quarter
    const int ib   = i4 * 8;           // i range [ib, ib+8)
    int wid = (blockIdx.x * blockDim.x + threadIdx.x) >> 6;
    wid = __builtin_amdgcn_readfirstlane(wid);
    const int nw = (gridDim.x * blockDim.x) >> 6;

    // ---- volatile preload: weight slice pinned in VGPRs (no remat) ----
    v2f wreg[8][8], breg[8];
    {
        const volatile v2f* wb = (const volatile v2f*)nn_b;
        const volatile v2f* ww = (const volatile v2f*)nn_w;
#pragma unroll
        for (int ii = 0; ii < 8; ++ii) {
            breg[ii] = wb[((ib + ii) * 32 + 2 * oo) >> 1];
#pragma unroll
            for (int k = 0; k < 8; ++k)
                wreg[k][ii] = ww[(k * 1024 + (ib + ii) * 32 + 2 * oo) >> 1];
        }
    }

    int K = 0;
    if (wid < N_EDGES) K = (N_EDGES - 1 - wid) / nw + 1;
    if (K == 0) return;

    struct Meta { int src, dst; float4 c0, c1; };

    auto load_meta = [&](Meta& M, int kk) {
        const int kc = kk < K ? kk : K - 1;
        const int e_ = wid + kc * nw;          // wave-uniform
        M.src = ei[e_];
        M.dst = ei[N_EDGES + e_];
        const float4* p_ = (const float4*)(ea + (size_t)e_ * 8);
        M.c0 = p_[0];
        M.c1 = p_[1];
    };

    auto fill_xs = [&](float4& A, float4& B, const Meta& M) {
        const float4* p_ = (const float4*)(x + (size_t)M.src * 32 + ib);
        A = p_[0];
        B = p_[1];
    };

    auto compute_edge = [&](const float4& XA, const float4& XB, const Meta& M) {
        v2f acc[8];
#pragma unroll
        for (int ii = 0; ii < 8; ++ii) acc[ii] = fma2(sp2(M.c0.x), wreg[0][ii], breg[ii]);
#pragma unroll
        for (int ii = 0; ii < 8; ++ii) acc[ii] = fma2(sp2(M.c0.y), wreg[1][ii], acc[ii]);
#pragma unroll
        for (int ii = 0; ii < 8; ++ii) acc[ii] = fma2(sp2(M.c0.z), wreg[2][ii], acc[ii]);
#pragma unroll
        for (int ii = 0; ii < 8; ++ii) acc[ii] = fma2(sp2(M.c0.w), wreg[3][ii], acc[ii]);
#pragma unroll
        for (int ii = 0; ii < 8; ++ii) acc[ii] = fma2(sp2(M.c1.x), wreg[4][ii], acc[ii]);
#pragma unroll
        for (int ii = 0; ii < 8; ++ii) acc[ii] = fma2(sp2(M.c1.y), wreg[5][ii], acc[ii]);
#pragma unroll
        for (int ii = 0; ii < 8; ++ii) acc[ii] = fma2(sp2(M.c1.z), wreg[6][ii], acc[ii]);
#pragma unroll
        for (int ii = 0; ii < 8; ++ii) acc[ii] = fma2(sp2(M.c1.w), wreg[7][ii], acc[ii]);
#pragma unroll
        for (int ii = 0; ii < 8; ++ii) acc[ii] = max2(acc[ii], sp2(0.f));

        v2f mm = acc[0] * sp2(XA.x);
        mm = fma2(sp2(XA.y), acc[1], mm);
        mm = fma2(sp2(XA.z), acc[2], mm);
        mm = fma2(sp2(XA.w), acc[3], mm);
        mm = fma2(sp2(XB.x), acc[4], mm);
        mm = fma2(sp2(XB.y), acc[5], mm);
        mm = fma2(sp2(XB.z), acc[6], mm);
        mm = fma2(sp2(XB.w), acc[7], mm);

        // reduce over the 4 i-quarters (lane stride 16)
        v2f t;
        t.x = __shfl_xor(mm.x, 16); t.y = __shfl_xor(mm.y, 16); mm += t;
        t.x = __shfl_xor(mm.x, 32); t.y = __shfl_xor(mm.y, 32); mm += t;

        if (lane < 16) {
            float* p_ = agg + (size_t)M.dst * 32 + 2 * oo;
            unsafeAtomicAdd(p_, mm.x);
            unsafeAtomicAdd(p_ + 1, mm.y);
        }
    };

    Meta ma, mb, mc;
    float4 xsA0, xsA1, xsB0, xsB1, xsC0, xsC1;

    load_meta(ma, 0); load_meta(mb, 1); load_meta(mc, 2);
    fill_xs(xsA0, xsA1, ma);
    fill_xs(xsB0, xsB1, mb);

    for (int k = 0; ; ) {
        fill_xs(xsC0, xsC1, mc);               // xs for edge k+2
        compute_edge(xsA0, xsA1, ma);          // edge k
        load_meta(ma, k + 3);
        if (++k >= K) break;

        fill_xs(xsA0, xsA1, ma);               // xs for edge k+3 (meta just loaded)
        compute_edge(xsB0, xsB1, mb);          // edge k+1
        load_meta(mb, k + 3);
        if (++k >= K) break;

        fill_xs(xsB0, xsB1, mb);               // xs for edge k+4
        compute_edge(xsC0, xsC1, mc);          // edge k+2
        load_meta(mc, k + 3);
        if (++k >= K) break;
    }
}

// ---------------------------------------------------------------------------
// Finalize (fused): h = agg + x@root + bias -> LayerNorm -> relu -> @lin_w+lin_b
// Wave per node-PAIR (two independent chains interleaved for ILP).
// Lane=(i2,o) for root matvec; LN via shfl butterflies; linear via (o2,j15).
// ---------------------------------------------------------------------------
__global__ __launch_bounds__(256) void finalize_kernel(
    const float* __restrict__ agg, const float* __restrict__ x,
    const float* __restrict__ root, const float* __restrict__ bias,
    const float* __restrict__ norm_w, const float* __restrict__ norm_b,
    const float* __restrict__ lin_w, const float* __restrict__ lin_b,
    float* __restrict__ out)
{
    const int lane  = threadIdx.x & 63;
    const int o     = lane & 31;
    const int ibase = (lane >> 5) * 16;
    const int wid   = (blockIdx.x * blockDim.x + threadIdx.x) >> 6;
    const int nw    = (gridDim.x * blockDim.x) >> 6;

    v2f rreg[8];
#pragma unroll
    for (int j = 0; j < 8; ++j) {
        const int i0 = ibase + 2 * j;
        v2f r; r.x = root[i0 * 32 + o]; r.y = root[(i0 + 1) * 32 + o];
        rreg[j] = r;
    }
#pragma unroll
    for (int j = 0; j < 8; ++j) asm volatile("" : "+v"(rreg[j]));

    const float bv  = bias[o];
    const float nwv = norm_w[o];
    const float nbv = norm_b[o];

    const int j15 = lane & 15;
    const int o2  = lane >> 4;
    float lwreg[8];
#pragma unroll
    for (int t = 0; t < 8; ++t) lwreg[t] = lin_w[(o2 * 8 + t) * 16 + j15];
    const float lbv = lin_b[j15];

    for (int p = wid; p < N_NODES / 2; p += nw) {
        const int n0 = 2 * p, n1 = 2 * p + 1;

        // root matvec, both nodes (independent)
        const v2f* xpa = (const v2f*)(x + (size_t)n0 * 32 + ibase);
        const v2f* xpb = (const v2f*)(x + (size_t)n1 * 32 + ibase);
        v2f r2a = sp2(0.f), r2b = sp2(0.f);
#pragma unroll
        for (int j = 0; j < 8; ++j) {
            r2a = fma2(xpa[j], rreg[j], r2a);
            r2b = fma2(xpb[j], rreg[j], r2b);
        }
        float ra = r2a.x + r2a.y;
        float rb = r2b.x + r2b.y;
        ra += __shfl_xor(ra, 32);
        rb += __shfl_xor(rb, 32);

        float hva = agg[(size_t)n0 * 32 + o] + ra + bv;
        float hvb = agg[(size_t)n1 * 32 + o] + rb + bv;

        // LayerNorm, interleaved chains
        float sa = hva, sb = hvb;
#pragma unroll
        for (int m = 1; m < 32; m <<= 1) {
            sa += __shfl_xor(sa, m);
            sb += __shfl_xor(sb, m);
        }
        const float mua = sa * (1.f / 32.f), mub = sb * (1.f / 32.f);
        const float da = hva - mua, db = hvb - mub;
        float qa = da * da, qb = db * db;
#pragma unroll
        for (int m = 1; m < 32; m <<= 1) {
            qa += __shfl_xor(qa, m);
            qb += __shfl_xor(qb, m);
        }
        const float rva = fmaxf(da * rsqrtf(qa * (1.f / 32.f) + 1e-5f) * nwv + nbv, 0.f);
        const float rvb = fmaxf(db * rsqrtf(qb * (1.f / 32.f) + 1e-5f) * nwv + nbv, 0.f);

        // linear 32->16, both nodes
        float acca = 0.f, accb = 0.f;
#pragma unroll
        for (int t = 0; t < 8; ++t) {
            const float va = __shfl(rva, o2 * 8 + t, 64);
            const float vb = __shfl(rvb, o2 * 8 + t, 64);
            acca = fmaf(va, lwreg[t], acca);
            accb = fmaf(vb, lwreg[t], accb);
        }
        acca += __shfl_xor(acca, 16);
        acca += __shfl_xor(acca, 32);
        accb += __shfl_xor(accb, 16);
        accb += __shfl_xor(accb, 32);
        if (lane < 16) {
            out[(size_t)n0 * 16 + lane] = acca + lbv;
            out[(size_t)n1 * 16 + lane] = accb + lbv;
        }
    }
}

// ---------------------------------------------------------------------------
extern "C" void kernel_launch(void* const* d_in, const int* in_sizes, int n_in,
                              void* d_out, int out_size, void* d_ws, size_t ws_size,
                              hipStream_t stream)
{
    const float* x      = (const float*)d_in[0];
    const int*   ei     = (const int*)  d_in[1];
    const float* ea     = (const float*)d_in[2];
    const float* nn_w   = (const float*)d_in[3];
    const float* nn_b   = (const float*)d_in[4];
    const float* root   = (const float*)d_in[5];
    const float* bias   = (const float*)d_in[6];
    const float* norm_w = (const float*)d_in[7];
    const float* norm_b = (const float*)d_in[8];
    const float* lin_w  = (const float*)d_in[9];
    const float* lin_b  = (const float*)d_in[10];
    float* out = (float*)d_out;

    float* agg = (float*)d_ws;   // N_NODES * 32 floats = 6.4 MB

    hipMemsetAsync(agg, 0, (size_t)N_NODES * 32 * sizeof(float), stream);
    edge_kernel<<<512, 256, 0, stream>>>(x, ei, ea, nn_w, nn_b, agg);
    finalize_kernel<<<2048, 256, 0, stream>>>(agg, x, root, bias, norm_w,
                                              norm_b, lin_w, lin_b, out);
}